// Round 3
// baseline (33.688 us; speedup 1.0000x reference)
//
#include <hip/hip_runtime.h>

#define KDIM 16
#define NSPIRAL 81

typedef float f4 __attribute__((ext_vector_type(4)));
typedef float f2 __attribute__((ext_vector_type(2)));

// spiral_pattern(4,4) flattened row-major (index c = y*9+x), values 1..81
__device__ __constant__ int d_spiral[NSPIRAL] = {
 74,73,72,71,70,69,68,67,66,
 75,44,43,42,41,40,39,38,65,
 76,45,22,21,20,19,18,37,64,
 77,46,23, 8, 7, 6,17,36,63,
 78,47,24, 9, 1, 5,16,35,62,
 79,48,25, 2, 3, 4,15,34,61,
 80,49,10,11,12,13,14,33,60,
 81,26,27,28,29,30,31,32,59,
 50,51,52,53,54,55,56,57,58
};

// C_CONST > 0: compile-time candidate count (guards fold). C_CONST < 0: runtime.
template<int C_CONST>
__global__ __launch_bounds__(256) void calc_vector_kernel(
    const float* __restrict__ windows,
    const float* __restrict__ templates,
    float* __restrict__ out,
    int npix, int C_rt)
{
    __shared__ int s_spiral[NSPIRAL];
    const int tid = threadIdx.x;
    if (tid < NSPIRAL) s_spiral[tid] = d_spiral[tid];
    __syncthreads();

    const int C    = (C_CONST > 0) ? C_CONST : C_rt;
    const int wave = tid >> 6;
    const int lane = tid & 63;
    const int wgid = blockIdx.x * 4 + wave;
    const int pix0 = wgid * 2;
    const int pix1 = pix0 + 1;
    if (pix0 >= npix) return;
    const bool has1 = (pix1 < npix);

    const int rowlen = C * KDIM;                 // 1312 floats
    const int nf4 = rowlen >> 2;                 // 328 float4s
    const float* wrow0 = windows + (size_t)pix0 * rowlen;
    const float* wrow1 = windows + (size_t)pix1 * rowlen;

    // each lane owns k-segment (lane&3)*4 of the template
    const int kseg = (lane & 3) * 4;
    const f4 tA = __builtin_nontemporal_load(
        reinterpret_cast<const f4*>(templates + (size_t)pix0 * KDIM + kseg));
    f4 tB = tA;
    if (has1) tB = __builtin_nontemporal_load(
        reinterpret_cast<const f4*>(templates + (size_t)pix1 * KDIM + kseg));

    // load both rows fully into registers (all indices compile-time after unroll)
    f4 a[6], b[6];
    #pragma unroll
    for (int it = 0; it < 6; ++it) {
        const int f = it * 64 + lane;
        const bool act = f < ((C_CONST > 0) ? (C_CONST * 4) : nf4);
        a[it] = f4{0.f, 0.f, 0.f, 0.f};
        b[it] = f4{0.f, 0.f, 0.f, 0.f};
        if (act) a[it] = __builtin_nontemporal_load(
            reinterpret_cast<const f4*>(wrow0 + f * 4));
        if (act && has1) b[it] = __builtin_nontemporal_load(
            reinterpret_cast<const f4*>(wrow1 + f * 4));
    }

    int bk0 = 0x7FFFFFFF, bk1 = 0x7FFFFFFF;
    int c810 = 0, c811 = 0;
    #pragma unroll
    for (int it = 0; it < 6; ++it) {
        const int f = it * 64 + lane;
        const int c = it * 16 + (lane >> 2);     // candidate this 4-lane group covers
        const bool act = f < ((C_CONST > 0) ? (C_CONST * 4) : nf4);
        float s0 = fabsf(a[it].x - tA.x) + fabsf(a[it].y - tA.y) +
                   fabsf(a[it].z - tA.z) + fabsf(a[it].w - tA.w);
        float s1 = fabsf(b[it].x - tB.x) + fabsf(b[it].y - tB.y) +
                   fabsf(b[it].z - tB.z) + fabsf(b[it].w - tB.w);
        s0 += __shfl_xor(s0, 1);  s1 += __shfl_xor(s1, 1);
        s0 += __shfl_xor(s0, 2);  s1 += __shfl_xor(s1, 2);
        if (act && c < NSPIRAL) {
            const int nb = (s_spiral[c] << 7) | c;
            bk0 = min(bk0, ((int)s0 << 14) | nb);
            bk1 = min(bk1, ((int)s1 << 14) | nb);
        }
        if (act && c == NSPIRAL) { c810 = (int)s0; c811 = (int)s1; }
    }

    // wave-wide min reduce of both packed keys (independent chains interleave)
    #pragma unroll
    for (int off = 32; off >= 1; off >>= 1) {
        bk0 = min(bk0, __shfl_xor(bk0, off));
        bk1 = min(bk1, __shfl_xor(bk1, off));
    }
    c810 = __shfl(c810, 4);
    c811 = __shfl(c811, 4);

    // pixel 0 winner
    const int idx0 = bk0 & 127, mc0 = bk0 >> 14;
    const bool m0  = c810 < mc0;
    const int mi0  = m0 ? NSPIRAL : idx0;
    const int mcv0 = min(c810, mc0);
    // pixel 1 winner
    const int idx1 = bk1 & 127, mc1 = bk1 >> 14;
    const bool m1  = c811 < mc1;
    const int mi1  = m1 ? NSPIRAL : idx1;
    const int mcv1 = min(c811, mc1);

    // extract winning candidate's 16 floats from saved registers (no refetch):
    // owning iteration mi>>4 is wave-uniform; source lane = (mi&15)*4 + (lane&3)
    f4 sel0, sel1;
    switch (mi0 >> 4) {
        case 0: sel0 = a[0]; break;  case 1: sel0 = a[1]; break;
        case 2: sel0 = a[2]; break;  case 3: sel0 = a[3]; break;
        case 4: sel0 = a[4]; break;  default: sel0 = a[5]; break;
    }
    switch (mi1 >> 4) {
        case 0: sel1 = b[0]; break;  case 1: sel1 = b[1]; break;
        case 2: sel1 = b[2]; break;  case 3: sel1 = b[3]; break;
        case 4: sel1 = b[4]; break;  default: sel1 = b[5]; break;
    }
    const int sl0 = (mi0 & 15) * 4 + (lane & 3);
    const int sl1 = (mi1 & 15) * 4 + (lane & 3);
    f4 win0, win1;
    win0.x = __shfl(sel0.x, sl0); win0.y = __shfl(sel0.y, sl0);
    win0.z = __shfl(sel0.z, sl0); win0.w = __shfl(sel0.w, sl0);
    win1.x = __shfl(sel1.x, sl1); win1.y = __shfl(sel1.y, sl1);
    win1.z = __shfl(sel1.z, sl1); win1.w = __shfl(sel1.w, sl1);

    // output layout: [vec: npix*2][tmpl: npix*16][mask: npix][cost: npix]
    float* out_vec  = out;
    float* out_tmpl = out + (size_t)npix * 2;
    float* out_mask = out + (size_t)npix * 18;
    float* out_cost = out + (size_t)npix * 19;

    // lanes 0..3 -> pix0 template, lanes 4..7 -> pix1 template (128B contiguous)
    if (lane < 8 && (lane < 4 || has1)) {
        const int  p = (lane < 4) ? pix0 : pix1;
        const f4   w = (lane < 4) ? win0 : win1;
        __builtin_nontemporal_store(w,
            reinterpret_cast<f4*>(out_tmpl + (size_t)p * KDIM + (lane & 3) * 4));
    }
    if (lane == 0) {
        if (has1) {
            f4 v; v.x = (float)(4 - idx0 / 9); v.y = (float)(4 - idx0 % 9);
                  v.z = (float)(4 - idx1 / 9); v.w = (float)(4 - idx1 % 9);
            __builtin_nontemporal_store(v,
                reinterpret_cast<f4*>(out_vec + (size_t)pix0 * 2));
            f2 mm; mm.x = m0 ? 1.f : 0.f; mm.y = m1 ? 1.f : 0.f;
            __builtin_nontemporal_store(mm,
                reinterpret_cast<f2*>(out_mask + pix0));
            f2 cc; cc.x = (float)mcv0; cc.y = (float)mcv1;
            __builtin_nontemporal_store(cc,
                reinterpret_cast<f2*>(out_cost + pix0));
        } else {
            f2 v; v.x = (float)(4 - idx0 / 9); v.y = (float)(4 - idx0 % 9);
            __builtin_nontemporal_store(v,
                reinterpret_cast<f2*>(out_vec + (size_t)pix0 * 2));
            out_mask[pix0] = m0 ? 1.f : 0.f;
            out_cost[pix0] = (float)mcv0;
        }
    }
}

extern "C" void kernel_launch(void* const* d_in, const int* in_sizes, int n_in,
                              void* d_out, int out_size, void* d_ws, size_t ws_size,
                              hipStream_t stream) {
    const float* windows   = (const float*)d_in[0];
    const float* templates = (const float*)d_in[1];
    float* out = (float*)d_out;

    const int npix = in_sizes[1] / KDIM;          // B*H*W = 32400
    const int C    = in_sizes[0] / in_sizes[1];   // 82

    const int npair  = (npix + 1) / 2;            // pixels processed in pairs
    const int blocks = (npair + 3) / 4;           // 4 waves (pairs) per block
    if (C == 82) {
        calc_vector_kernel<82><<<blocks, 256, 0, stream>>>(windows, templates, out, npix, C);
    } else {
        calc_vector_kernel<-1><<<blocks, 256, 0, stream>>>(windows, templates, out, npix, C);
    }
}